// Round 9
// baseline (313.315 us; speedup 1.0000x reference)
//
#include <hip/hip_runtime.h>

#pragma clang fp contract(off)

#define N_PRE   6000
#define N_POST  300
#define NW      94          // 64-bit words per mask row (ceil(6000/64))
#define SELCAP  7936        // 124*64 pool capacity (top-6000 + digit-bucket ties)
#define RS_BLK  124
#define NBIN    16384       // 14-bit digit histogram
#define DSHIFT  18          // digit = s32 >> 18
#define HPART   64          // partial histogram copies

struct SelState {
    unsigned int thr;       // 14-bit digit threshold: keep if (s32>>DSHIFT) >= thr
};

// ---------------------------------------------------------------------------
// 1. decode + clip + valid + sortable 32-bit score key (pure streaming).
// Blocks 0/1 also zero sel / valid_words / counter (replaces memset node).
// ---------------------------------------------------------------------------
__global__ void decode_kernel(const float4* __restrict__ deltas,
                              const float4* __restrict__ anchors,
                              const float*  __restrict__ scores,
                              const int* __restrict__ ph, const int* __restrict__ pw,
                              const int* __restrict__ ps,
                              unsigned int* __restrict__ s32out,
                              float4* __restrict__ boxes,
                              unsigned long long* __restrict__ sel,
                              unsigned long long* __restrict__ valid_words,
                              unsigned int* __restrict__ counter, int N)
{
#pragma clang fp contract(off)
    if (blockIdx.x == 0) {
        for (int t = threadIdx.x; t < SELCAP; t += 256) sel[t] = 0ull;
    } else if (blockIdx.x == 1) {
        if (threadIdx.x < 128) valid_words[threadIdx.x] = 0ull;
        if (threadIdx.x == 0) *counter = 0u;
    }
    int i = blockIdx.x * blockDim.x + threadIdx.x;
    if (i >= N) return;
    float H = (float)(*ph), W = (float)(*pw), S = (float)(*ps);
    float4 d = deltas[i];
    float4 a = anchors[i];
    float h = a.z - a.x, w = a.w - a.y;
    float cy = a.x + 0.5f * h, cx = a.y + 0.5f * w;
    float ncy = d.x * h + cy;
    float ncx = d.y * w + cx;
    float eh = (float)exp((double)d.z);   // correctly-rounded f32 exp
    float ew = (float)exp((double)d.w);
    float nh = eh * h;
    float nw = ew * w;
    float ymin = ncy - 0.5f * nh, xmin = ncx - 0.5f * nw;
    float ymax = ncy + 0.5f * nh, xmax = ncx + 0.5f * nw;
    ymin = fminf(fmaxf(ymin, 0.0f), H);
    xmin = fminf(fmaxf(xmin, 0.0f), W);
    ymax = fminf(fmaxf(ymax, 0.0f), H);
    xmax = fminf(fmaxf(xmax, 0.0f), W);
    bool valid = (ymax - ymin >= S) && (xmax - xmin >= S);
    float sc = scores[i];
    unsigned int bits = __float_as_uint(sc);
    unsigned int s32;
    if (!valid) s32 = 0x007FFFFFu;   // sortable encoding of -inf
    else        s32 = (bits & 0x80000000u) ? ~bits : (bits | 0x80000000u);
    s32out[i] = s32;
    boxes[i]  = make_float4(ymin, xmin, ymax, xmax);
}

// ---------------------------------------------------------------------------
// 2a. LDS-privatized partial histograms (no global atomics)
// ---------------------------------------------------------------------------
__global__ __launch_bounds__(256) void hist_part(const unsigned int* __restrict__ s32in,
                                                 unsigned int* __restrict__ phist, int N)
{
    __shared__ unsigned int lh[NBIN];   // 64 KiB
    int tid = threadIdx.x;
    for (int j = tid; j < NBIN; j += 256) lh[j] = 0u;
    __syncthreads();
    for (int i = blockIdx.x * 256 + tid; i < N; i += HPART * 256)
        atomicAdd(&lh[s32in[i] >> DSHIFT], 1u);
    __syncthreads();
    unsigned int* dst = phist + blockIdx.x * NBIN;
    for (int j = tid; j < NBIN; j += 256) dst[j] = lh[j];
}

// ---------------------------------------------------------------------------
// 2b. reduce partials -> hist (atomic-free, coalesced)
// ---------------------------------------------------------------------------
__global__ __launch_bounds__(256) void hist_reduce(const unsigned int* __restrict__ phist,
                                                   unsigned int* __restrict__ hist)
{
    int j = blockIdx.x * 256 + threadIdx.x;   // NBIN/256 = 64 blocks
    unsigned int s = 0;
#pragma unroll 8
    for (int b = 0; b < HPART; b++) s += phist[b * NBIN + j];
    hist[j] = s;
}

// ---------------------------------------------------------------------------
// 3. pick: thr = max 14-bit digit with suffix-count(>= thr) >= 6000
// ---------------------------------------------------------------------------
__global__ __launch_bounds__(1024) void pick_pass(const unsigned int* __restrict__ hist,
                                                  SelState* __restrict__ state)
{
    __shared__ unsigned int wsum[16];
    __shared__ int sel_chunk;
    __shared__ unsigned int sel_above;
    int tid = threadIdx.x, lane = tid & 63, wave = tid >> 6;
    const unsigned int k = 6000u;

    unsigned int s = 0;
    int base = tid * 16;
#pragma unroll
    for (int i = 0; i < 16; i++) s += hist[base + i];
    unsigned int S = s;
    for (int d = 1; d < 64; d <<= 1) {
        unsigned int t = __shfl_down(S, d);
        if (lane + d < 64) S += t;
    }
    if (lane == 0) wsum[wave] = S;
    __syncthreads();
    unsigned int above = 0;
    for (int w2 = wave + 1; w2 < 16; w2++) above += wsum[w2];
    unsigned int F  = S + above;   // suffix including chunk tid
    unsigned int Fn = F - s;       // suffix excluding chunk tid
    if (Fn < k && k <= F) { sel_chunk = tid; sel_above = Fn; }
    __syncthreads();
    int c = sel_chunk;
    unsigned int acc = sel_above;
    if (wave == 0 && lane < 16) {
        unsigned int b = hist[c * 16 + lane];
        unsigned int B = b;
        for (int d = 1; d < 16; d <<= 1) {
            unsigned int t = __shfl_down(B, d);
            if (lane + d < 16) B += t;
        }
        unsigned int Bn = B - b;
        unsigned int kk = k - acc;
        if (Bn < kk && kk <= B) state->thr = (unsigned int)(c * 16 + lane);
    }
}

// ---------------------------------------------------------------------------
// 4. compact: pool = all elements whose 14-bit digit >= thr (>=6000, <=cap)
// ---------------------------------------------------------------------------
__global__ void compact_kernel(const unsigned int* __restrict__ s32in,
                               const SelState* __restrict__ state,
                               unsigned long long* __restrict__ sel,
                               unsigned int* __restrict__ counter, int N)
{
    int i = blockIdx.x * blockDim.x + threadIdx.x;
    if (i >= N) return;
    unsigned int s32 = s32in[i];
    if ((s32 >> DSHIFT) >= state->thr) {
        unsigned int p = atomicAdd(counter, 1u);
        if (p < SELCAP)
            sel[p] = ((unsigned long long)s32 << 32) |
                     (unsigned long long)(~(unsigned int)i);
    }
}

// ---------------------------------------------------------------------------
// 5. exact rank by count over full 64-bit keys; scatter boxes + valid bits
// ---------------------------------------------------------------------------
__global__ __launch_bounds__(256) void rank_scatter(
    const unsigned long long* __restrict__ sel,   // SELCAP entries, zero-padded
    const float4* __restrict__ boxes,
    float4* __restrict__ boxes_sorted,
    unsigned long long* __restrict__ valid_words, int N)
{
    __shared__ __align__(16) unsigned long long kbuf[SELCAP];   // 62 KiB
    __shared__ unsigned int cnt4[4][64];
    int tid = threadIdx.x;
    for (int t = tid; t < SELCAP; t += 256) kbuf[t] = sel[t];
    __syncthreads();
    int lane = tid & 63;
    int slice = tid >> 6;                 // 0..3
    int i = blockIdx.x * 64 + lane;       // my key slot
    unsigned long long my = kbuf[i];
    const int SL = SELCAP / 4;            // 1984
    int j0 = slice * SL;
    unsigned int c = 0;
#pragma unroll 8
    for (int j = j0; j < j0 + SL; j += 2) {
        ulonglong2 kk = *reinterpret_cast<const ulonglong2*>(&kbuf[j]);
        c += (kk.x > my) || (kk.x == my && j < i);
        c += (kk.y > my) || (kk.y == my && (j + 1) < i);
    }
    cnt4[slice][lane] = c;
    __syncthreads();
    if (tid < 64) {
        unsigned int rank = cnt4[0][tid] + cnt4[1][tid] + cnt4[2][tid] + cnt4[3][tid];
        unsigned long long key = kbuf[blockIdx.x * 64 + tid];
        if (key != 0ull && rank < N_PRE) {
            unsigned int s32 = (unsigned int)(key >> 32);
            unsigned int ii  = ~(unsigned int)(key & 0xFFFFFFFFull);
            float4 b = (ii < (unsigned int)N) ? boxes[ii] : make_float4(0.f,0.f,0.f,0.f);
            boxes_sorted[rank] = b;
            bool v = (s32 != 0x007FFFFFu) && (ii < (unsigned int)N);
            if (v) atomicOr(&valid_words[rank >> 6], 1ull << (rank & 63));
        }
    }
}

// ---------------------------------------------------------------------------
// 6. pairwise suppression mask, upper triangle only (incl. diagonal word)
// ---------------------------------------------------------------------------
__global__ __launch_bounds__(64) void mask_kernel(const float4* __restrict__ boxes_sorted,
                                                  unsigned long long* __restrict__ mask)
{
#pragma clang fp contract(off)
    int rb = blockIdx.y, cb = blockIdx.x;
    if (cb < rb) return;
    __shared__ float4 cbox[64];
    int tid = threadIdx.x;
    int col0 = cb * 64;
    int c = col0 + tid;
    cbox[tid] = (c < N_PRE) ? boxes_sorted[c] : make_float4(0.f, 0.f, 0.f, 0.f);
    __syncthreads();
    int i = rb * 64 + tid;
    if (i >= N_PRE) return;
    float4 bi = boxes_sorted[i];
    float area_i = (bi.z - bi.x) * (bi.w - bi.y);
    unsigned long long word = 0ull;
#pragma unroll 8
    for (int j = 0; j < 64; j++) {
        float4 bj = cbox[j];
        float iy = fminf(bi.z, bj.z) - fmaxf(bi.x, bj.x);
        iy = fmaxf(iy, 0.0f);
        float ix = fminf(bi.w, bj.w) - fmaxf(bi.y, bj.y);
        ix = fmaxf(ix, 0.0f);
        float inter = iy * ix;
        float area_j = (bj.z - bj.x) * (bj.w - bj.y);
        float iou = inter / (((area_i + area_j) - inter) + 1e-9f);
        if ((col0 + j) > i && iou > 0.7f) word |= (1ull << j);
    }
    mask[(size_t)i * NW + cb] = word;
}

// ---------------------------------------------------------------------------
// 7. word-sequential greedy NMS, diag-resolve + 2-word-pipelined row-OR:
//    - lane l preloads its row's diag word (w) and band word (w+1)
//    - keep-step: 1x shfl64 diag (alive update) + 1x shfl64 band (carry),
//      issued in parallel; no IoU, no ballot in the loop
//    - kept rows' full-row ORs (coalesced) issued at word w, awaited at w+2;
//      word w+1 is covered by the register carry
// ---------------------------------------------------------------------------
__global__ __launch_bounds__(64) void nms_seq(const unsigned long long* __restrict__ mask,
                                              const unsigned long long* __restrict__ valid_words,
                                              const float4* __restrict__ boxes_sorted,
                                              float* __restrict__ out)
{
#pragma clang fp contract(off)
    int lane = threadIdx.x;
    float4* out4 = reinterpret_cast<float4*>(out);

    for (int t = lane; t < N_POST; t += 64)
        out4[t] = make_float4(0.f, 0.f, 0.f, 0.f);

    unsigned long long vw0 = valid_words[lane];
    unsigned long long vw1 = (lane < NW - 64) ? valid_words[64 + lane] : 0ull;
    unsigned long long rem0 = ~vw0;
    unsigned long long rem1 = ~vw1;

    // two pending row-OR generations (registers; all indexing compile-time)
    unsigned long long pA_lo[8] = {0,0,0,0,0,0,0,0}, pA_hi[8] = {0,0,0,0,0,0,0,0};
    unsigned long long pB_lo[8] = {0,0,0,0,0,0,0,0}, pB_hi[8] = {0,0,0,0,0,0,0,0};

    unsigned long long carry = 0ull;
    int rank = 0;

    // prologue: word-0 data
    int row0 = lane;
    unsigned long long dg_d = mask[(size_t)row0 * NW + 0];
    unsigned long long dg_b = mask[(size_t)row0 * NW + 1];
    float4 cb = boxes_sorted[lane];

#define WORD_STEP(WV, PLO, PHI)                                                 \
    {                                                                           \
        int w = (WV);                                                           \
        /* apply pending row-ORs issued two words ago (latency hidden) */       \
        rem0 |= ((PLO[0]|PLO[1])|(PLO[2]|PLO[3]))|((PLO[4]|PLO[5])|(PLO[6]|PLO[7])); \
        rem1 |= ((PHI[0]|PHI[1])|(PHI[2]|PHI[3]))|((PHI[4]|PHI[5])|(PHI[6]|PHI[7])); \
        /* prefetch next word's diag/band/boxes (keep-independent addrs) */     \
        unsigned long long dgn_d = 0ull, dgn_b = 0ull;                          \
        float4 cbn = cb;                                                        \
        if (w + 1 < NW) {                                                       \
            int rown = (w + 1) * 64 + lane;                                     \
            if (rown > N_PRE - 1) rown = N_PRE - 1;                             \
            dgn_d = mask[(size_t)rown * NW + (w + 1)];                          \
            dgn_b = mask[(size_t)rown * NW + (w + 2)];                          \
            cbn = boxes_sorted[(w + 1) * 64 + lane];                            \
        }                                                                       \
        unsigned long long remw = (w < 64) ? __shfl(rem0, w) : __shfl(rem1, w - 64); \
        unsigned long long vw   = (w < 64) ? __shfl(vw0, w)  : __shfl(vw1, w - 64); \
        unsigned long long alive = vw & ~remw & ~carry;                         \
        carry = 0ull;                                                           \
        unsigned long long keptb = 0ull;                                        \
        while (alive) {                                                         \
            int b = __builtin_ctzll(alive);      /* wave-uniform */             \
            unsigned long long dxb = __shfl(dg_d, b);                           \
            unsigned long long dyb = __shfl(dg_b, b);                           \
            if (lane == b) out4[rank] = cb;                                     \
            keptb |= 1ull << b;                                                 \
            rank++;                                                             \
            if (rank >= N_POST) break;                                          \
            alive &= ~(dxb | (1ull << b));                                      \
            carry |= dyb;                                                       \
        }                                                                       \
        if (rank >= N_POST) break;                                              \
        /* issue this word's kept-row ORs (coalesced, <=8 slots) */             \
        {                                                                       \
            int kc = __popcll(keptb);                                           \
            unsigned long long kb = keptb;                                      \
            _Pragma("unroll")                                                   \
            for (int sslot = 0; sslot < 8; sslot++) {                           \
                if (sslot < kc) {                                               \
                    int bb = __builtin_ctzll(kb); kb &= kb - 1ull;              \
                    const unsigned long long* rp = mask + (size_t)(w * 64 + bb) * NW; \
                    PLO[sslot] = rp[lane];                                      \
                    PHI[sslot] = (lane < NW - 64) ? rp[64 + lane] : 0ull;       \
                } else { PLO[sslot] = 0ull; PHI[sslot] = 0ull; }                \
            }                                                                   \
            while (kb) {  /* rare: >8 keeps in one word, sync apply */          \
                int bb = __builtin_ctzll(kb); kb &= kb - 1ull;                  \
                const unsigned long long* rp = mask + (size_t)(w * 64 + bb) * NW; \
                rem0 |= rp[lane];                                               \
                if (lane < NW - 64) rem1 |= rp[64 + lane];                      \
            }                                                                   \
        }                                                                       \
        dg_d = dgn_d; dg_b = dgn_b; cb = cbn;                                   \
    }

    for (int w2 = 0; w2 < NW; w2 += 2) {
        WORD_STEP(w2,     pA_lo, pA_hi)
        WORD_STEP(w2 + 1, pB_lo, pB_hi)
    }
#undef WORD_STEP
}

// ---------------------------------------------------------------------------
extern "C" void kernel_launch(void* const* d_in, const int* in_sizes, int n_in,
                              void* d_out, int out_size, void* d_ws, size_t ws_size,
                              hipStream_t stream)
{
    const float4* deltas  = (const float4*)d_in[0];
    const float4* anchors = (const float4*)d_in[1];
    const float*  scores  = (const float*)d_in[2];
    const int* ph = (const int*)d_in[3];
    const int* pw = (const int*)d_in[4];
    const int* ps = (const int*)d_in[5];
    int N = in_sizes[2];

    char* base = (char*)d_ws;
    size_t off = 0;
    auto alloc = [&](size_t sz) -> void* {
        void* p = base + off;
        off = (off + sz + 255) & ~(size_t)255;
        return p;
    };
    unsigned int* s32buf = (unsigned int*)alloc(sizeof(unsigned int) * (size_t)N);
    float4* boxes = (float4*)alloc(sizeof(float4) * (size_t)N);
    unsigned int* phist = (unsigned int*)alloc((size_t)HPART * NBIN * sizeof(unsigned int));
    unsigned int* hist = (unsigned int*)alloc(NBIN * sizeof(unsigned int));
    SelState* state = (SelState*)alloc(256);
    unsigned int* counter = (unsigned int*)alloc(256);
    unsigned long long* valid_words = (unsigned long long*)alloc(128 * 8);
    unsigned long long* sel = (unsigned long long*)alloc(sizeof(unsigned long long) * SELCAP);
    float4* boxes_sorted = (float4*)alloc(sizeof(float4) * 6016);
    // +32 elements padding: band prefetch at w=93 reads up to 2 words past row 5999
    unsigned long long* mask = (unsigned long long*)alloc(sizeof(unsigned long long) * ((size_t)N_PRE * NW + 32));

    int nb = (N + 255) / 256;
    decode_kernel<<<nb, 256, 0, stream>>>(deltas, anchors, scores, ph, pw, ps,
                                          s32buf, boxes, sel, valid_words, counter, N);
    hist_part<<<HPART, 256, 0, stream>>>(s32buf, phist, N);
    hist_reduce<<<NBIN / 256, 256, 0, stream>>>(phist, hist);
    pick_pass<<<1, 1024, 0, stream>>>(hist, state);
    compact_kernel<<<nb, 256, 0, stream>>>(s32buf, state, sel, counter, N);
    rank_scatter<<<RS_BLK, 256, 0, stream>>>(sel, boxes, boxes_sorted, valid_words, N);
    mask_kernel<<<dim3(NW, NW), 64, 0, stream>>>(boxes_sorted, mask);
    nms_seq<<<1, 64, 0, stream>>>(mask, valid_words, boxes_sorted, (float*)d_out);
}

// Round 10
// 263.433 us; speedup vs baseline: 1.1894x; 1.1894x over previous
//
#include <hip/hip_runtime.h>

#pragma clang fp contract(off)

#define N_PRE   6000
#define N_POST  300
#define NW      94          // 64-bit words per mask row (ceil(6000/64))
#define SELCAP  7936        // 124*64 pool capacity (top-6000 + digit-bucket ties)
#define RS_BLK  124
#define NBIN    16384       // 14-bit digit histogram
#define DSHIFT  18          // digit = s32 >> 18
#define HPART   64          // partial histogram copies

struct SelState {
    unsigned int thr;       // 14-bit digit threshold: keep if (s32>>DSHIFT) >= thr
};

static __device__ __forceinline__ unsigned long long readlane64(unsigned long long v, int l) {
    unsigned lo = __builtin_amdgcn_readlane((unsigned)v, l);
    unsigned hi = __builtin_amdgcn_readlane((unsigned)(v >> 32), l);
    return ((unsigned long long)hi << 32) | lo;
}

// ---------------------------------------------------------------------------
// 1. decode + clip + valid + sortable 32-bit score key (pure streaming).
// Blocks 0/1 also zero sel / valid_words / counter (replaces memset node).
// ---------------------------------------------------------------------------
__global__ void decode_kernel(const float4* __restrict__ deltas,
                              const float4* __restrict__ anchors,
                              const float*  __restrict__ scores,
                              const int* __restrict__ ph, const int* __restrict__ pw,
                              const int* __restrict__ ps,
                              unsigned int* __restrict__ s32out,
                              float4* __restrict__ boxes,
                              unsigned long long* __restrict__ sel,
                              unsigned long long* __restrict__ valid_words,
                              unsigned int* __restrict__ counter, int N)
{
#pragma clang fp contract(off)
    if (blockIdx.x == 0) {
        for (int t = threadIdx.x; t < SELCAP; t += 256) sel[t] = 0ull;
    } else if (blockIdx.x == 1) {
        if (threadIdx.x < 128) valid_words[threadIdx.x] = 0ull;
        if (threadIdx.x == 0) *counter = 0u;
    }
    int i = blockIdx.x * blockDim.x + threadIdx.x;
    if (i >= N) return;
    float H = (float)(*ph), W = (float)(*pw), S = (float)(*ps);
    float4 d = deltas[i];
    float4 a = anchors[i];
    float h = a.z - a.x, w = a.w - a.y;
    float cy = a.x + 0.5f * h, cx = a.y + 0.5f * w;
    float ncy = d.x * h + cy;
    float ncx = d.y * w + cx;
    float eh = (float)exp((double)d.z);   // correctly-rounded f32 exp
    float ew = (float)exp((double)d.w);
    float nh = eh * h;
    float nw = ew * w;
    float ymin = ncy - 0.5f * nh, xmin = ncx - 0.5f * nw;
    float ymax = ncy + 0.5f * nh, xmax = ncx + 0.5f * nw;
    ymin = fminf(fmaxf(ymin, 0.0f), H);
    xmin = fminf(fmaxf(xmin, 0.0f), W);
    ymax = fminf(fmaxf(ymax, 0.0f), H);
    xmax = fminf(fmaxf(xmax, 0.0f), W);
    bool valid = (ymax - ymin >= S) && (xmax - xmin >= S);
    float sc = scores[i];
    unsigned int bits = __float_as_uint(sc);
    unsigned int s32;
    if (!valid) s32 = 0x007FFFFFu;   // sortable encoding of -inf
    else        s32 = (bits & 0x80000000u) ? ~bits : (bits | 0x80000000u);
    s32out[i] = s32;
    boxes[i]  = make_float4(ymin, xmin, ymax, xmax);
}

// ---------------------------------------------------------------------------
// 2a. LDS-privatized partial histograms (no global atomics)
// ---------------------------------------------------------------------------
__global__ __launch_bounds__(256) void hist_part(const unsigned int* __restrict__ s32in,
                                                 unsigned int* __restrict__ phist, int N)
{
    __shared__ unsigned int lh[NBIN];   // 64 KiB
    int tid = threadIdx.x;
    for (int j = tid; j < NBIN; j += 256) lh[j] = 0u;
    __syncthreads();
    for (int i = blockIdx.x * 256 + tid; i < N; i += HPART * 256)
        atomicAdd(&lh[s32in[i] >> DSHIFT], 1u);
    __syncthreads();
    unsigned int* dst = phist + blockIdx.x * NBIN;
    for (int j = tid; j < NBIN; j += 256) dst[j] = lh[j];
}

// ---------------------------------------------------------------------------
// 2b. reduce partials -> hist (atomic-free, coalesced)
// ---------------------------------------------------------------------------
__global__ __launch_bounds__(256) void hist_reduce(const unsigned int* __restrict__ phist,
                                                   unsigned int* __restrict__ hist)
{
    int j = blockIdx.x * 256 + threadIdx.x;   // NBIN/256 = 64 blocks
    unsigned int s = 0;
#pragma unroll 8
    for (int b = 0; b < HPART; b++) s += phist[b * NBIN + j];
    hist[j] = s;
}

// ---------------------------------------------------------------------------
// 3. pick: thr = max 14-bit digit with suffix-count(>= thr) >= 6000
// ---------------------------------------------------------------------------
__global__ __launch_bounds__(1024) void pick_pass(const unsigned int* __restrict__ hist,
                                                  SelState* __restrict__ state)
{
    __shared__ unsigned int wsum[16];
    __shared__ int sel_chunk;
    __shared__ unsigned int sel_above;
    int tid = threadIdx.x, lane = tid & 63, wave = tid >> 6;
    const unsigned int k = 6000u;

    unsigned int s = 0;
    int base = tid * 16;
#pragma unroll
    for (int i = 0; i < 16; i++) s += hist[base + i];
    unsigned int S = s;
    for (int d = 1; d < 64; d <<= 1) {
        unsigned int t = __shfl_down(S, d);
        if (lane + d < 64) S += t;
    }
    if (lane == 0) wsum[wave] = S;
    __syncthreads();
    unsigned int above = 0;
    for (int w2 = wave + 1; w2 < 16; w2++) above += wsum[w2];
    unsigned int F  = S + above;   // suffix including chunk tid
    unsigned int Fn = F - s;       // suffix excluding chunk tid
    if (Fn < k && k <= F) { sel_chunk = tid; sel_above = Fn; }
    __syncthreads();
    int c = sel_chunk;
    unsigned int acc = sel_above;
    if (wave == 0 && lane < 16) {
        unsigned int b = hist[c * 16 + lane];
        unsigned int B = b;
        for (int d = 1; d < 16; d <<= 1) {
            unsigned int t = __shfl_down(B, d);
            if (lane + d < 16) B += t;
        }
        unsigned int Bn = B - b;
        unsigned int kk = k - acc;
        if (Bn < kk && kk <= B) state->thr = (unsigned int)(c * 16 + lane);
    }
}

// ---------------------------------------------------------------------------
// 4. compact: pool = all elements whose 14-bit digit >= thr (>=6000, <=cap)
// ---------------------------------------------------------------------------
__global__ void compact_kernel(const unsigned int* __restrict__ s32in,
                               const SelState* __restrict__ state,
                               unsigned long long* __restrict__ sel,
                               unsigned int* __restrict__ counter, int N)
{
    int i = blockIdx.x * blockDim.x + threadIdx.x;
    if (i >= N) return;
    unsigned int s32 = s32in[i];
    if ((s32 >> DSHIFT) >= state->thr) {
        unsigned int p = atomicAdd(counter, 1u);
        if (p < SELCAP)
            sel[p] = ((unsigned long long)s32 << 32) |
                     (unsigned long long)(~(unsigned int)i);
    }
}

// ---------------------------------------------------------------------------
// 5. exact rank by count over full 64-bit keys; scatter boxes + valid bits
//    1024 threads: 16 slices of 496 keys each -> ~4x less serial VALU/thread
// ---------------------------------------------------------------------------
__global__ __launch_bounds__(1024) void rank_scatter(
    const unsigned long long* __restrict__ sel,   // SELCAP entries, zero-padded
    const float4* __restrict__ boxes,
    float4* __restrict__ boxes_sorted,
    unsigned long long* __restrict__ valid_words, int N)
{
    __shared__ __align__(16) unsigned long long kbuf[SELCAP];   // 62 KiB
    __shared__ unsigned int cnt[64];
    int tid = threadIdx.x;
    if (tid < 64) cnt[tid] = 0u;
    for (int t = tid; t < SELCAP; t += 1024) kbuf[t] = sel[t];
    __syncthreads();
    int lane = tid & 63;
    int slice = tid >> 6;                 // 0..15
    int i = blockIdx.x * 64 + lane;       // my key slot
    unsigned long long my = kbuf[i];
    const int SL = SELCAP / 16;           // 496
    int j0 = slice * SL;
    unsigned int c = 0;
#pragma unroll 8
    for (int j = j0; j < j0 + SL; j += 2) {
        ulonglong2 kk = *reinterpret_cast<const ulonglong2*>(&kbuf[j]);
        c += (kk.x > my) || (kk.x == my && j < i);
        c += (kk.y > my) || (kk.y == my && (j + 1) < i);
    }
    atomicAdd(&cnt[lane], c);
    __syncthreads();
    if (tid < 64) {
        unsigned int rank = cnt[tid];
        unsigned long long key = kbuf[blockIdx.x * 64 + tid];
        if (key != 0ull && rank < N_PRE) {
            unsigned int s32 = (unsigned int)(key >> 32);
            unsigned int ii  = ~(unsigned int)(key & 0xFFFFFFFFull);
            float4 b = (ii < (unsigned int)N) ? boxes[ii] : make_float4(0.f,0.f,0.f,0.f);
            boxes_sorted[rank] = b;
            bool v = (s32 != 0x007FFFFFu) && (ii < (unsigned int)N);
            if (v) atomicOr(&valid_words[rank >> 6], 1ull << (rank & 63));
        }
    }
}

// ---------------------------------------------------------------------------
// 6. pairwise suppression mask, upper triangle only (incl. diagonal word).
//    Diagonal blocks also emit the TRANSPOSED 64x64 bit-block (diagT); the
//    first superdiagonal emits the transposed band block (bandT). Transposes
//    cost 64 ballots in an already-parallel kernel and let nms_seq resolve
//    keeps with register bit-tests instead of ds_bpermute shuffles.
// ---------------------------------------------------------------------------
__global__ __launch_bounds__(64) void mask_kernel(const float4* __restrict__ boxes_sorted,
                                                  unsigned long long* __restrict__ mask,
                                                  unsigned long long* __restrict__ diagT,
                                                  unsigned long long* __restrict__ bandT)
{
#pragma clang fp contract(off)
    int rb = blockIdx.y, cb = blockIdx.x;
    if (cb < rb) return;
    __shared__ float4 cbox[64];
    int tid = threadIdx.x;
    int col0 = cb * 64;
    int c = col0 + tid;
    cbox[tid] = (c < N_PRE) ? boxes_sorted[c] : make_float4(0.f, 0.f, 0.f, 0.f);
    __syncthreads();
    int i = rb * 64 + tid;
    if (i >= N_PRE) return;
    float4 bi = boxes_sorted[i];
    float area_i = (bi.z - bi.x) * (bi.w - bi.y);
    unsigned long long word = 0ull;
#pragma unroll 8
    for (int j = 0; j < 64; j++) {
        float4 bj = cbox[j];
        float iy = fminf(bi.z, bj.z) - fmaxf(bi.x, bj.x);
        iy = fmaxf(iy, 0.0f);
        float ix = fminf(bi.w, bj.w) - fmaxf(bi.y, bj.y);
        ix = fmaxf(ix, 0.0f);
        float inter = iy * ix;
        float area_j = (bj.z - bj.x) * (bj.w - bj.y);
        float iou = inter / (((area_i + area_j) - inter) + 1e-9f);
        if ((col0 + j) > i && iou > 0.7f) word |= (1ull << j);
    }
    mask[(size_t)i * NW + cb] = word;

    if (cb == rb || cb == rb + 1) {
        unsigned long long colw = 0ull;
        for (int jj = 0; jj < 64; jj++) {
            unsigned long long t = __ballot((unsigned int)((word >> jj) & 1ull));
            if (tid == jj) colw = t;
        }
        if (cb == rb) diagT[rb * 64 + tid] = colw;
        else          bandT[rb * 64 + tid] = colw;
    }
}

// ---------------------------------------------------------------------------
// 7. word-sequential greedy NMS, scalar/register resolve:
//    - lane j holds diagT/bandT COLUMN words: keep-step = register bit-test
//      + one ballot (v_cmp->vcc) -- no ds_bpermute in the serial chain
//    - word broadcasts (rem/valid) via readlane (uniform index, VALU-cheap)
//    - kept rows' full-row ORs issued at word w, applied at w+2 (latency
//      hidden); word w+1 covered by the bandT carry ballot
// ---------------------------------------------------------------------------
__global__ __launch_bounds__(64) void nms_seq(const unsigned long long* __restrict__ mask,
                                              const unsigned long long* __restrict__ diagT,
                                              const unsigned long long* __restrict__ bandT,
                                              const unsigned long long* __restrict__ valid_words,
                                              const float4* __restrict__ boxes_sorted,
                                              float* __restrict__ out)
{
#pragma clang fp contract(off)
    int lane = threadIdx.x;
    float4* out4 = reinterpret_cast<float4*>(out);

    for (int t = lane; t < N_POST; t += 64)
        out4[t] = make_float4(0.f, 0.f, 0.f, 0.f);

    unsigned long long vw0 = valid_words[lane];
    unsigned long long vw1 = (lane < NW - 64) ? valid_words[64 + lane] : 0ull;
    unsigned long long rem0 = ~vw0;
    unsigned long long rem1 = ~vw1;

    // two pending row-OR generations (compile-time indexed registers)
    unsigned long long pA_lo[8] = {0,0,0,0,0,0,0,0}, pA_hi[8] = {0,0,0,0,0,0,0,0};
    unsigned long long pB_lo[8] = {0,0,0,0,0,0,0,0}, pB_hi[8] = {0,0,0,0,0,0,0,0};

    unsigned long long carryword = 0ull;
    int rank = 0;

    // word-0 data: column words + candidate box
    unsigned long long dT = diagT[lane];
    unsigned long long bT = bandT[lane];
    float4 cb = boxes_sorted[lane];

#define WORD_STEP(WV, PLO, PHI)                                                 \
    {                                                                           \
        int w = (WV);                                                           \
        /* apply pending row-ORs issued two words ago (latency hidden) */       \
        rem0 |= ((PLO[0]|PLO[1])|(PLO[2]|PLO[3]))|((PLO[4]|PLO[5])|(PLO[6]|PLO[7])); \
        rem1 |= ((PHI[0]|PHI[1])|(PHI[2]|PHI[3]))|((PHI[4]|PHI[5])|(PHI[6]|PHI[7])); \
        /* prefetch next word's columns/boxes (keep-independent addrs) */       \
        unsigned long long dTn = 0ull, bTn = 0ull;                              \
        float4 cbn = cb;                                                        \
        if (w + 1 < NW) {                                                       \
            dTn = diagT[(w + 1) * 64 + lane];                                   \
            bTn = bandT[(w + 1) * 64 + lane];                                   \
            cbn = boxes_sorted[(w + 1) * 64 + lane];                            \
        }                                                                       \
        unsigned long long remw = (w < 64) ? readlane64(rem0, w)                \
                                           : readlane64(rem1, w - 64);          \
        unsigned long long vw   = (w < 64) ? readlane64(vw0, w)                 \
                                           : readlane64(vw1, w - 64);           \
        unsigned long long alive = vw & ~remw & ~carryword;                     \
        unsigned int carryacc = 0u;                                             \
        unsigned long long keptb = 0ull;                                        \
        while (alive) {                                                         \
            int b = __builtin_ctzll(alive);      /* wave-uniform */             \
            unsigned int supme = (unsigned int)((dT >> b) & 1ull);              \
            carryacc |= (unsigned int)((bT >> b) & 1ull);                       \
            if (lane == b) out4[rank] = cb;                                     \
            keptb |= 1ull << b;                                                 \
            rank++;                                                             \
            if (rank >= N_POST) break;                                          \
            unsigned long long supw = __ballot(supme);                          \
            alive &= ~(supw | (1ull << b));                                     \
        }                                                                       \
        if (rank >= N_POST) break;                                              \
        carryword = __ballot(carryacc);                                         \
        /* issue this word's kept-row ORs (coalesced, <=8 slots) */             \
        {                                                                       \
            int kc = __popcll(keptb);                                           \
            unsigned long long kb = keptb;                                      \
            _Pragma("unroll")                                                   \
            for (int sslot = 0; sslot < 8; sslot++) {                           \
                if (sslot < kc) {                                               \
                    int bb = __builtin_ctzll(kb); kb &= kb - 1ull;              \
                    const unsigned long long* rp = mask + (size_t)(w * 64 + bb) * NW; \
                    PLO[sslot] = rp[lane];                                      \
                    PHI[sslot] = (lane < NW - 64) ? rp[64 + lane] : 0ull;       \
                } else { PLO[sslot] = 0ull; PHI[sslot] = 0ull; }                \
            }                                                                   \
            while (kb) {  /* rare: >8 keeps in one word, sync apply */          \
                int bb = __builtin_ctzll(kb); kb &= kb - 1ull;                  \
                const unsigned long long* rp = mask + (size_t)(w * 64 + bb) * NW; \
                rem0 |= rp[lane];                                               \
                if (lane < NW - 64) rem1 |= rp[64 + lane];                      \
            }                                                                   \
        }                                                                       \
        dT = dTn; bT = bTn; cb = cbn;                                           \
    }

    for (int w2 = 0; w2 < NW; w2 += 2) {
        WORD_STEP(w2,     pA_lo, pA_hi)
        WORD_STEP(w2 + 1, pB_lo, pB_hi)
    }
#undef WORD_STEP
}

// ---------------------------------------------------------------------------
extern "C" void kernel_launch(void* const* d_in, const int* in_sizes, int n_in,
                              void* d_out, int out_size, void* d_ws, size_t ws_size,
                              hipStream_t stream)
{
    const float4* deltas  = (const float4*)d_in[0];
    const float4* anchors = (const float4*)d_in[1];
    const float*  scores  = (const float*)d_in[2];
    const int* ph = (const int*)d_in[3];
    const int* pw = (const int*)d_in[4];
    const int* ps = (const int*)d_in[5];
    int N = in_sizes[2];

    char* base = (char*)d_ws;
    size_t off = 0;
    auto alloc = [&](size_t sz) -> void* {
        void* p = base + off;
        off = (off + sz + 255) & ~(size_t)255;
        return p;
    };
    unsigned int* s32buf = (unsigned int*)alloc(sizeof(unsigned int) * (size_t)N);
    float4* boxes = (float4*)alloc(sizeof(float4) * (size_t)N);
    unsigned int* phist = (unsigned int*)alloc((size_t)HPART * NBIN * sizeof(unsigned int));
    unsigned int* hist = (unsigned int*)alloc(NBIN * sizeof(unsigned int));
    SelState* state = (SelState*)alloc(256);
    unsigned int* counter = (unsigned int*)alloc(256);
    unsigned long long* valid_words = (unsigned long long*)alloc(128 * 8);
    unsigned long long* sel = (unsigned long long*)alloc(sizeof(unsigned long long) * SELCAP);
    float4* boxes_sorted = (float4*)alloc(sizeof(float4) * 6016);
    unsigned long long* diagT = (unsigned long long*)alloc(sizeof(unsigned long long) * NW * 64);
    unsigned long long* bandT = (unsigned long long*)alloc(sizeof(unsigned long long) * NW * 64);
    unsigned long long* mask = (unsigned long long*)alloc(sizeof(unsigned long long) * ((size_t)N_PRE * NW + 32));

    int nb = (N + 255) / 256;
    decode_kernel<<<nb, 256, 0, stream>>>(deltas, anchors, scores, ph, pw, ps,
                                          s32buf, boxes, sel, valid_words, counter, N);
    hist_part<<<HPART, 256, 0, stream>>>(s32buf, phist, N);
    hist_reduce<<<NBIN / 256, 256, 0, stream>>>(phist, hist);
    pick_pass<<<1, 1024, 0, stream>>>(hist, state);
    compact_kernel<<<nb, 256, 0, stream>>>(s32buf, state, sel, counter, N);
    rank_scatter<<<RS_BLK, 1024, 0, stream>>>(sel, boxes, boxes_sorted, valid_words, N);
    mask_kernel<<<dim3(NW, NW), 64, 0, stream>>>(boxes_sorted, mask, diagT, bandT);
    nms_seq<<<1, 64, 0, stream>>>(mask, diagT, bandT, valid_words, boxes_sorted, (float*)d_out);
}